// Round 2
// baseline (4619.063 us; speedup 1.0000x reference)
//
#include <hip/hip_runtime.h>
#include <math.h>

#define N_USERS 8192
#define DIMS    128
#define EDGES   262144
#define KCAND   131072
#define NTOT    (EDGES + KCAND)      // 393216
#define QCAP    48                   // per-(row,quarter) candidate capacity
#define NCELLS  (N_USERS * 4)        // 32768 (row, quarter) cells
#define COS_THR 0.3f

// ---------------------------------------------------------------------------
// 1) normalize: replicate numpy pairwise-sum norm (8 accumulators + tree),
//    correctly-rounded sqrt via double, precise fp32 division.  (bit-exact,
//    passed R1 with absmax 0 — do not touch)
// ---------------------------------------------------------------------------
__global__ __launch_bounds__(256) void normalize_k(const float* __restrict__ x,
                                                   float* __restrict__ u) {
#pragma clang fp contract(off)
  int i = blockIdx.x * 256 + threadIdx.x;
  if (i >= N_USERS) return;
  const float* r = x + (size_t)i * DIMS;
  float a[8];
#pragma unroll
  for (int j = 0; j < 8; ++j) { float t = r[j]; a[j] = t * t; }
  for (int b8 = 8; b8 < DIMS; b8 += 8) {
#pragma unroll
    for (int j = 0; j < 8; ++j) { float t = r[b8 + j]; a[j] = a[j] + t * t; }
  }
  float s = ((a[0] + a[1]) + (a[2] + a[3])) + ((a[4] + a[5]) + (a[6] + a[7]));
  float n = (float)sqrt((double)s);
  n = fmaxf(n, 1e-12f);
  for (int k = 0; k < DIMS; ++k) u[(size_t)i * DIMS + k] = r[k] / n;
}

// ---------------------------------------------------------------------------
// 2) exclusion bitmask from nonzero_idx (8192 x 256 words)
// ---------------------------------------------------------------------------
__global__ __launch_bounds__(256) void build_excl(const int* __restrict__ nz,
                                                  unsigned* __restrict__ excl) {
  int t = blockIdx.x * 256 + threadIdx.x;
  if (t >= EDGES) return;
  int i = nz[2 * t], j = nz[2 * t + 1];
  atomicOr(&excl[(size_t)i * 256 + (j >> 5)], 1u << (j & 31));
}

// ---------------------------------------------------------------------------
// 3) pass_a: fp32 cos GEMM.
//    Grid 512: block = (64 rows) x (2048-col quarter q), 8 j-tiles of 256.
//    4 waves; wave w computes rows 16w..16w+15 x all 256 cols of the tile.
//    Per-lane tile 16x4 (cols 4*lane..4*lane+3).
//    B tile staged k-major in LDS via register 4x4 transpose ->
//    ds_write_b128 of contiguous 1KB rows (conflict-free); global loads
//    prefetched into registers during previous chunk's compute.
//    A rows staged once; read as broadcast b128 (free).
//    Candidates bucketed per (row, quarter) to preserve global row-major,
//    ascending-j order.  Accumulation: sequential-k fmaf (bitwise == numpy).
// ---------------------------------------------------------------------------
__global__ __launch_bounds__(256, 2) void pass_a(const float* __restrict__ u,
                                                 const unsigned* __restrict__ excl,
                                                 int* __restrict__ rowjq,
                                                 float* __restrict__ rowvq,
                                                 int* __restrict__ row_cnt4) {
  __shared__ float rowsA[64][132];   // [row][k]   132*4 = 528 B stride (16B-mult)
  __shared__ float colsB[32][260];   // [k][col]   260*4 = 1040 B stride (16B-mult)

  const int tid  = threadIdx.x;
  const int lane = tid & 63;
  const int wv   = tid >> 6;
  const int rblk = blockIdx.x >> 2;
  const int q    = blockIdx.x & 3;
  const int r0   = rblk * 64;
  const int jq0  = q * 2048;

  // stage this block's 64 rows of u (once)
#pragma unroll
  for (int it = 0; it < 8; ++it) {
    int idx = tid + it * 256;
    int row = idx >> 5, c4 = idx & 31;
    float4 f = ((const float4*)(u + (size_t)(r0 + row) * DIMS))[c4];
    *(float4*)&rowsA[row][c4 * 4] = f;
  }

  float acc[16][4];
  int cnt[16];
#pragma unroll
  for (int rr = 0; rr < 16; ++rr) cnt[rr] = 0;

  const unsigned long long below = (1ull << lane) - 1ull;
  const int gi0 = r0 + wv * 16;

  // staging prefetch registers: pfr[s][c][t] = u[(jb+4l+c)*128 + kc+8w+4s+t]
  float pfr[2][4][4];
#define DO_PREFETCH(CS)                                                       \
  {                                                                           \
    int jb_ = jq0 + ((CS) >> 2) * 256;                                        \
    int kc_ = ((CS) & 3) * 32;                                                \
    _Pragma("unroll")                                                         \
    for (int s = 0; s < 2; ++s) {                                             \
      _Pragma("unroll")                                                       \
      for (int c = 0; c < 4; ++c) {                                           \
        float4 f = *(const float4*)(u + (size_t)(jb_ + 4 * lane + c) * DIMS + \
                                    kc_ + 8 * wv + 4 * s);                    \
        pfr[s][c][0] = f.x; pfr[s][c][1] = f.y;                               \
        pfr[s][c][2] = f.z; pfr[s][c][3] = f.w;                               \
      }                                                                       \
    }                                                                         \
  }

  DO_PREFETCH(0)

#pragma unroll 1
  for (int cs = 0; cs < 32; ++cs) {
    const int kc = (cs & 3) * 32;
    if ((cs & 3) == 0) {
#pragma unroll
      for (int rr = 0; rr < 16; ++rr)
#pragma unroll
        for (int cc = 0; cc < 4; ++cc) acc[rr][cc] = 0.f;
    }

    __syncthreads();   // previous chunk's colsB reads complete
    // write staged chunk: wave w owns ks [8w, 8w+8); each instr writes a
    // full contiguous 1KB LDS row (conflict-free)
#pragma unroll
    for (int s = 0; s < 2; ++s)
#pragma unroll
      for (int t = 0; t < 4; ++t) {
        float4 v;
        v.x = pfr[s][0][t]; v.y = pfr[s][1][t];
        v.z = pfr[s][2][t]; v.w = pfr[s][3][t];
        *(float4*)&colsB[8 * wv + 4 * s + t][4 * lane] = v;
      }
    __syncthreads();

    if (cs + 1 < 32) DO_PREFETCH(cs + 1)   // hide L2 latency under compute

    // compute: 8 k4-steps x (4 col b128 + 16 row-broadcast b128 + 256 FMA)
#pragma unroll
    for (int k4 = 0; k4 < 8; ++k4) {
      float cvf[4][4];
#pragma unroll
      for (int kk = 0; kk < 4; ++kk) {
        float4 f = *(const float4*)&colsB[k4 * 4 + kk][4 * lane];
        cvf[kk][0] = f.x; cvf[kk][1] = f.y; cvf[kk][2] = f.z; cvf[kk][3] = f.w;
      }
#pragma unroll
      for (int rr = 0; rr < 16; ++rr) {
        float4 rv = *(const float4*)&rowsA[wv * 16 + rr][kc + k4 * 4];
        float rvf[4];
        rvf[0] = rv.x; rvf[1] = rv.y; rvf[2] = rv.z; rvf[3] = rv.w;
#pragma unroll
        for (int kk = 0; kk < 4; ++kk)
#pragma unroll
          for (int cc = 0; cc < 4; ++cc)
            acc[rr][cc] = fmaf(rvf[kk], cvf[kk][cc], acc[rr][cc]);
      }
    }

    // candidate scan after last chunk of each j-tile
    if ((cs & 3) == 3) {
      const int jb = jq0 + (cs >> 2) * 256;
      const int jcol0 = jb + lane * 4;
#pragma unroll
      for (int rr = 0; rr < 16; ++rr) {
        const int gi = gi0 + rr;
        unsigned word = excl[(size_t)gi * 256 + (jb >> 5) + (lane >> 3)];
        int bitbase = (lane & 7) * 4;
        bool pred[4];
        unsigned long long m[4];
#pragma unroll
        for (int cc = 0; cc < 4; ++cc) {
          float v = acc[rr][cc];
          pred[cc] = (v > COS_THR) && !((word >> (bitbase + cc)) & 1u) &&
                     (jcol0 + cc != gi);
          m[cc] = __ballot(pred[cc]);
        }
        int before = __popcll(m[0] & below) + __popcll(m[1] & below) +
                     __popcll(m[2] & below) + __popcll(m[3] & below);
        int base = cnt[rr] + before;
        int sub = 0;
        size_t cell = ((size_t)gi * 4 + q) * QCAP;
#pragma unroll
        for (int cc = 0; cc < 4; ++cc) {
          if (pred[cc]) {
            int idx = base + sub;
            if (idx < QCAP) {
              rowjq[cell + idx] = jcol0 + cc;
              rowvq[cell + idx] = acc[rr][cc];
            }
            ++sub;
          }
        }
        cnt[rr] += __popcll(m[0]) + __popcll(m[1]) +
                   __popcll(m[2]) + __popcll(m[3]);
      }
    }
  }

  if (lane == 0) {
#pragma unroll
    for (int rr = 0; rr < 16; ++rr)
      row_cnt4[(size_t)(gi0 + rr) * 4 + q] = min(cnt[rr], QCAP);
  }
#undef DO_PREFETCH
}

// ---------------------------------------------------------------------------
// 4) exclusive prefix scan over 32768 (row,quarter) counts — single block,
//    serial-128-per-thread + one 256-wide Hillis-Steele (9 barriers total)
// ---------------------------------------------------------------------------
__global__ __launch_bounds__(256) void scan_rows(const int* __restrict__ cnt,
                                                 int* __restrict__ off) {
  __shared__ int sm[256];
  int t = threadIdx.x;
  int base = t * 128;
  int s = 0;
  for (int i = 0; i < 128; ++i) s += cnt[base + i];
  sm[t] = s;
  __syncthreads();
  int x = s;
  for (int d = 1; d < 256; d <<= 1) {
    int y = (t >= d) ? sm[t - d] : 0;
    __syncthreads();
    x += y;
    sm[t] = x;
    __syncthreads();
  }
  int run = x - s;  // exclusive prefix
  for (int i = 0; i < 128; ++i) { off[base + i] = run; run += cnt[base + i]; }
  if (t == 255) off[NCELLS] = x;
}

// ---------------------------------------------------------------------------
// 5) compact per-cell buffers into the global candidate list
// ---------------------------------------------------------------------------
__global__ __launch_bounds__(256) void compact_rows(const int* __restrict__ cnt4,
                                                    const int* __restrict__ off,
                                                    const int* __restrict__ rowjq,
                                                    const float* __restrict__ rowvq,
                                                    int* __restrict__ cand_i,
                                                    int* __restrict__ cand_j,
                                                    float* __restrict__ cand_v) {
  int cell = blockIdx.x * 256 + threadIdx.x;
  if (cell >= NCELLS) return;
  int n = cnt4[cell], o0 = off[cell];
  int row = cell >> 2;
  for (int t = 0; t < n; ++t) {
    int o = o0 + t;
    if (o < KCAND) {
      cand_i[o] = row;
      cand_j[o] = rowjq[(size_t)cell * QCAP + t];
      cand_v[o] = rowvq[(size_t)cell * QCAP + t];
    }
  }
}

// 5b) pad the tail [M, K): nonzero fill_value=0, cand_val = cos[0,0] = -1
__global__ __launch_bounds__(256) void pad_cands(const int* __restrict__ off,
                                                 int* __restrict__ cand_i,
                                                 int* __restrict__ cand_j,
                                                 float* __restrict__ cand_v) {
  int t = blockIdx.x * 256 + threadIdx.x;
  if (t >= KCAND) return;
  int M = off[NCELLS];
  if (t >= M) { cand_i[t] = 0; cand_j[t] = 0; cand_v[t] = -1.0f; }
}

// ---------------------------------------------------------------------------
// 6) finalize: logits (sequential 256-term fmaf chain, matching BLAS order),
//    gumbel argmax, weights, all three outputs.  (bit-exact, passed R1)
// ---------------------------------------------------------------------------
__global__ __launch_bounds__(256) void finalize_k(const float* __restrict__ ue,
                                                  const float* __restrict__ W,
                                                  const float* __restrict__ b,
                                                  const float* __restrict__ g,
                                                  const int* __restrict__ nz,
                                                  const int* __restrict__ cand_i,
                                                  const int* __restrict__ cand_j,
                                                  const float* __restrict__ cand_v,
                                                  float* __restrict__ out) {
  __shared__ float Ws[512];
  int tid = threadIdx.x;
  Ws[tid] = W[tid];
  Ws[tid + 256] = W[tid + 256];
  __syncthreads();

  int p = blockIdx.x * 256 + tid;
  if (p >= NTOT) return;

  int i, j;
  float wgt;
  if (p < EDGES) {
    i = nz[2 * p];
    j = nz[2 * p + 1];
    wgt = 1.0f;
  } else {
    int qq = p - EDGES;
    i = cand_i[qq];
    j = cand_j[qq];
    wgt = fmaxf(cand_v[qq], 0.0f);
  }

  const float4* ri = (const float4*)(ue + (size_t)i * DIMS);
  const float4* rj = (const float4*)(ue + (size_t)j * DIMS);
  float l0 = 0.f, l1 = 0.f;
#pragma unroll
  for (int kk = 0; kk < 32; ++kk) {
    float4 a = ri[kk];
    l0 = fmaf(a.x, Ws[kk * 4 + 0], l0);
    l0 = fmaf(a.y, Ws[kk * 4 + 1], l0);
    l0 = fmaf(a.z, Ws[kk * 4 + 2], l0);
    l0 = fmaf(a.w, Ws[kk * 4 + 3], l0);
    l1 = fmaf(a.x, Ws[256 + kk * 4 + 0], l1);
    l1 = fmaf(a.y, Ws[256 + kk * 4 + 1], l1);
    l1 = fmaf(a.z, Ws[256 + kk * 4 + 2], l1);
    l1 = fmaf(a.w, Ws[256 + kk * 4 + 3], l1);
  }
#pragma unroll
  for (int kk = 0; kk < 32; ++kk) {
    float4 a = rj[kk];
    l0 = fmaf(a.x, Ws[128 + kk * 4 + 0], l0);
    l0 = fmaf(a.y, Ws[128 + kk * 4 + 1], l0);
    l0 = fmaf(a.z, Ws[128 + kk * 4 + 2], l0);
    l0 = fmaf(a.w, Ws[128 + kk * 4 + 3], l0);
    l1 = fmaf(a.x, Ws[384 + kk * 4 + 0], l1);
    l1 = fmaf(a.y, Ws[384 + kk * 4 + 1], l1);
    l1 = fmaf(a.z, Ws[384 + kk * 4 + 2], l1);
    l1 = fmaf(a.w, Ws[384 + kk * 4 + 3], l1);
  }
  l0 += b[0];
  l1 += b[1];

  float s0 = l0 + g[2 * p];
  float s1 = l1 + g[2 * p + 1];
  float w = (s0 >= s1) ? wgt : 0.0f;

  out[p] = w;
  out[NTOT + p] = w;
  out[2 * NTOT + p] = w;
  out[3 * NTOT + 2 * p + 0] = (float)i;
  out[3 * NTOT + 2 * p + 1] = (float)j;
}

// ---------------------------------------------------------------------------
extern "C" void kernel_launch(void* const* d_in, const int* in_sizes, int n_in,
                              void* d_out, int out_size, void* d_ws, size_t ws_size,
                              hipStream_t stream) {
  (void)in_sizes; (void)n_in; (void)out_size; (void)ws_size;

  const float* user_emb = (const float*)d_in[0];
  const float* W        = (const float*)d_in[1];
  const float* b        = (const float*)d_in[2];
  const float* gnoise   = (const float*)d_in[3];
  const int*   nz       = (const int*)d_in[4];
  float* out = (float*)d_out;

  char* ws = (char*)d_ws;
  // ws layout (bytes)
  float*    u        = (float*)(ws + 0);                       //  4 MB
  unsigned* excl     = (unsigned*)(ws + (4u << 20));           //  8 MB
  int*      rowjq    = (int*)(ws + (12u << 20));               //  6 MB (32768*48*4)
  float*    rowvq    = (float*)(ws + (18u << 20));             //  6 MB
  int*      row_cnt4 = (int*)(ws + (24u << 20));               //  128 KB
  int*      row_off  = (int*)(ws + (24u << 20) + (256u << 10)); // 32769 ints
  int*      cand_i   = (int*)(ws + (25u << 20));               //  512 KB
  int*      cand_j   = (int*)(ws + (25u << 20) + (512u << 10));
  float*    cand_v   = (float*)(ws + (26u << 20));

  hipMemsetAsync(excl, 0, (size_t)N_USERS * 256 * sizeof(unsigned), stream);

  normalize_k<<<N_USERS / 256, 256, 0, stream>>>(user_emb, u);
  build_excl<<<EDGES / 256, 256, 0, stream>>>(nz, excl);
  pass_a<<<512, 256, 0, stream>>>(u, excl, rowjq, rowvq, row_cnt4);
  scan_rows<<<1, 256, 0, stream>>>(row_cnt4, row_off);
  compact_rows<<<NCELLS / 256, 256, 0, stream>>>(row_cnt4, row_off, rowjq, rowvq,
                                                 cand_i, cand_j, cand_v);
  pad_cands<<<KCAND / 256, 256, 0, stream>>>(row_off, cand_i, cand_j, cand_v);
  finalize_k<<<NTOT / 256, 256, 0, stream>>>(user_emb, W, b, gnoise, nz,
                                             cand_i, cand_j, cand_v, out);
}

// Round 3
// 652.369 us; speedup vs baseline: 7.0805x; 7.0805x over previous
//
#include <hip/hip_runtime.h>
#include <math.h>

#define N_USERS 8192
#define DIMS    128
#define EDGES   262144
#define KCAND   131072
#define NTOT    (EDGES + KCAND)      // 393216
#define QCAP    48                   // per-(row,quarter) candidate capacity
#define NCELLS  (N_USERS * 4)        // 32768 (row, quarter) cells
#define COS_THR 0.3f

// ---------------------------------------------------------------------------
// 1) normalize — bit-exact vs numpy (pairwise 8-acc + tree, double sqrt).
// ---------------------------------------------------------------------------
__global__ __launch_bounds__(256) void normalize_k(const float* __restrict__ x,
                                                   float* __restrict__ u) {
#pragma clang fp contract(off)
  int i = blockIdx.x * 256 + threadIdx.x;
  if (i >= N_USERS) return;
  const float* r = x + (size_t)i * DIMS;
  float a[8];
#pragma unroll
  for (int j = 0; j < 8; ++j) { float t = r[j]; a[j] = t * t; }
  for (int b8 = 8; b8 < DIMS; b8 += 8) {
#pragma unroll
    for (int j = 0; j < 8; ++j) { float t = r[b8 + j]; a[j] = a[j] + t * t; }
  }
  float s = ((a[0] + a[1]) + (a[2] + a[3])) + ((a[4] + a[5]) + (a[6] + a[7]));
  float n = (float)sqrt((double)s);
  n = fmaxf(n, 1e-12f);
  for (int k = 0; k < DIMS; ++k) u[(size_t)i * DIMS + k] = r[k] / n;
}

// ---------------------------------------------------------------------------
// 2) exclusion bitmask from nonzero_idx (8192 x 256 words)
// ---------------------------------------------------------------------------
__global__ __launch_bounds__(256) void build_excl(const int* __restrict__ nz,
                                                  unsigned* __restrict__ excl) {
  int t = blockIdx.x * 256 + threadIdx.x;
  if (t >= EDGES) return;
  int i = nz[2 * t], j = nz[2 * t + 1];
  atomicOr(&excl[(size_t)i * 256 + (j >> 5)], 1u << (j & 31));
}

// ---------------------------------------------------------------------------
// 3) pass_a: fp32 cos GEMM.
//    Grid 1024: block = (32 rows) x (2048-col quarter q), 8 j-tiles of 256.
//    4 waves; wave w computes rows 8w..8w+7 x 256 cols; lane tile 8x4.
//    Register budget: acc 32 + pfr 32 + misc ~35 -> ~100 VGPR, NO spill
//    (R2's 16x4 tile + launch_bounds(256,2) capped VGPR at 128 and spilled
//    accumulators to scratch: 14 GB HBM traffic. Keep tile at 8x4.)
//    LDS scheme from R2 (measured conflict-free): B staged k-major via
//    register 4x4 transpose + ds_write_b128 of contiguous 1KB rows;
//    k-major b128 col reads; broadcast b128 row reads.
//    Accumulation: sequential-k fmaf (bitwise == numpy BLAS order).
// ---------------------------------------------------------------------------
__global__ __launch_bounds__(256) void pass_a(const float* __restrict__ u,
                                              const unsigned* __restrict__ excl,
                                              int* __restrict__ rowjq,
                                              float* __restrict__ rowvq,
                                              int* __restrict__ row_cnt4) {
  __shared__ float rowsA[32][132];   // [row][k]   528 B stride (16B multiple)
  __shared__ float colsB[32][260];   // [k][col]   1040 B stride (16B multiple)

  const int tid  = threadIdx.x;
  const int lane = tid & 63;
  const int wv   = tid >> 6;
  const int rblk = blockIdx.x >> 2;
  const int q    = blockIdx.x & 3;
  const int r0   = rblk * 32;
  const int jq0  = q * 2048;

  // stage this block's 32 rows of u (once)
#pragma unroll
  for (int it = 0; it < 4; ++it) {
    int idx = tid + it * 256;
    int row = idx >> 5, c4 = idx & 31;
    float4 f = ((const float4*)(u + (size_t)(r0 + row) * DIMS))[c4];
    *(float4*)&rowsA[row][c4 * 4] = f;
  }

  float acc[8][4];
  int cnt[8];
#pragma unroll
  for (int rr = 0; rr < 8; ++rr) cnt[rr] = 0;

  const unsigned long long below = (1ull << lane) - 1ull;
  const int gi0 = r0 + wv * 8;

  // staging prefetch registers: pfr[s][c][t] = u[(jb+4l+c)*128 + kc+8w+4s+t]
  float pfr[2][4][4];
#define DO_PREFETCH(CS)                                                       \
  {                                                                           \
    int jb_ = jq0 + ((CS) >> 2) * 256;                                        \
    int kc_ = ((CS) & 3) * 32;                                                \
    _Pragma("unroll")                                                         \
    for (int s = 0; s < 2; ++s) {                                             \
      _Pragma("unroll")                                                       \
      for (int c = 0; c < 4; ++c) {                                           \
        float4 f = *(const float4*)(u + (size_t)(jb_ + 4 * lane + c) * DIMS + \
                                    kc_ + 8 * wv + 4 * s);                    \
        pfr[s][c][0] = f.x; pfr[s][c][1] = f.y;                               \
        pfr[s][c][2] = f.z; pfr[s][c][3] = f.w;                               \
      }                                                                       \
    }                                                                         \
  }

  DO_PREFETCH(0)

#pragma unroll 1
  for (int cs = 0; cs < 32; ++cs) {
    const int kc = (cs & 3) * 32;
    if ((cs & 3) == 0) {
#pragma unroll
      for (int rr = 0; rr < 8; ++rr)
#pragma unroll
        for (int cc = 0; cc < 4; ++cc) acc[rr][cc] = 0.f;
    }

    __syncthreads();   // previous chunk's colsB reads complete
    // wave w stages ks [8w, 8w+8): each instr writes a full contiguous
    // 1KB LDS row (conflict-free, measured 0 in R2)
#pragma unroll
    for (int s = 0; s < 2; ++s)
#pragma unroll
      for (int t = 0; t < 4; ++t) {
        float4 v;
        v.x = pfr[s][0][t]; v.y = pfr[s][1][t];
        v.z = pfr[s][2][t]; v.w = pfr[s][3][t];
        *(float4*)&colsB[8 * wv + 4 * s + t][4 * lane] = v;
      }
    __syncthreads();

    if (cs + 1 < 32) DO_PREFETCH(cs + 1)   // hide L2 latency under compute

    // compute: 8 k4-steps x (4 col b128 + 8 row-broadcast b128 + 128 FMA)
#pragma unroll
    for (int k4 = 0; k4 < 8; ++k4) {
      float cvf[4][4];
#pragma unroll
      for (int kk = 0; kk < 4; ++kk) {
        float4 f = *(const float4*)&colsB[k4 * 4 + kk][4 * lane];
        cvf[kk][0] = f.x; cvf[kk][1] = f.y; cvf[kk][2] = f.z; cvf[kk][3] = f.w;
      }
#pragma unroll
      for (int rr = 0; rr < 8; ++rr) {
        float4 rv = *(const float4*)&rowsA[wv * 8 + rr][kc + k4 * 4];
        float rvf[4];
        rvf[0] = rv.x; rvf[1] = rv.y; rvf[2] = rv.z; rvf[3] = rv.w;
#pragma unroll
        for (int kk = 0; kk < 4; ++kk)
#pragma unroll
          for (int cc = 0; cc < 4; ++cc)
            acc[rr][cc] = fmaf(rvf[kk], cvf[kk][cc], acc[rr][cc]);
      }
    }

    // candidate scan after last chunk of each j-tile
    if ((cs & 3) == 3) {
      const int jb = jq0 + (cs >> 2) * 256;
      const int jcol0 = jb + lane * 4;
#pragma unroll
      for (int rr = 0; rr < 8; ++rr) {
        const int gi = gi0 + rr;
        unsigned word = excl[(size_t)gi * 256 + (jb >> 5) + (lane >> 3)];
        int bitbase = (lane & 7) * 4;
        bool pred[4];
        unsigned long long m[4];
#pragma unroll
        for (int cc = 0; cc < 4; ++cc) {
          float v = acc[rr][cc];
          pred[cc] = (v > COS_THR) && !((word >> (bitbase + cc)) & 1u) &&
                     (jcol0 + cc != gi);
          m[cc] = __ballot(pred[cc]);
        }
        int before = __popcll(m[0] & below) + __popcll(m[1] & below) +
                     __popcll(m[2] & below) + __popcll(m[3] & below);
        int base = cnt[rr] + before;
        int sub = 0;
        size_t cell = ((size_t)gi * 4 + q) * QCAP;
#pragma unroll
        for (int cc = 0; cc < 4; ++cc) {
          if (pred[cc]) {
            int idx = base + sub;
            if (idx < QCAP) {
              rowjq[cell + idx] = jcol0 + cc;
              rowvq[cell + idx] = acc[rr][cc];
            }
            ++sub;
          }
        }
        cnt[rr] += __popcll(m[0]) + __popcll(m[1]) +
                   __popcll(m[2]) + __popcll(m[3]);
      }
    }
  }

  if (lane == 0) {
#pragma unroll
    for (int rr = 0; rr < 8; ++rr)
      row_cnt4[(size_t)(gi0 + rr) * 4 + q] = min(cnt[rr], QCAP);
  }
#undef DO_PREFETCH
}

// ---------------------------------------------------------------------------
// 4) exclusive prefix scan over 32768 (row,quarter) counts — single block
// ---------------------------------------------------------------------------
__global__ __launch_bounds__(256) void scan_rows(const int* __restrict__ cnt,
                                                 int* __restrict__ off) {
  __shared__ int sm[256];
  int t = threadIdx.x;
  int base = t * 128;
  int s = 0;
  for (int i = 0; i < 128; ++i) s += cnt[base + i];
  sm[t] = s;
  __syncthreads();
  int x = s;
  for (int d = 1; d < 256; d <<= 1) {
    int y = (t >= d) ? sm[t - d] : 0;
    __syncthreads();
    x += y;
    sm[t] = x;
    __syncthreads();
  }
  int run = x - s;  // exclusive prefix
  for (int i = 0; i < 128; ++i) { off[base + i] = run; run += cnt[base + i]; }
  if (t == 255) off[NCELLS] = x;
}

// ---------------------------------------------------------------------------
// 5) compact per-cell buffers into the global candidate list
// ---------------------------------------------------------------------------
__global__ __launch_bounds__(256) void compact_rows(const int* __restrict__ cnt4,
                                                    const int* __restrict__ off,
                                                    const int* __restrict__ rowjq,
                                                    const float* __restrict__ rowvq,
                                                    int* __restrict__ cand_i,
                                                    int* __restrict__ cand_j,
                                                    float* __restrict__ cand_v) {
  int cell = blockIdx.x * 256 + threadIdx.x;
  if (cell >= NCELLS) return;
  int n = cnt4[cell], o0 = off[cell];
  int row = cell >> 2;
  for (int t = 0; t < n; ++t) {
    int o = o0 + t;
    if (o < KCAND) {
      cand_i[o] = row;
      cand_j[o] = rowjq[(size_t)cell * QCAP + t];
      cand_v[o] = rowvq[(size_t)cell * QCAP + t];
    }
  }
}

// 5b) pad the tail [M, K): nonzero fill_value=0, cand_val = cos[0,0] = -1
__global__ __launch_bounds__(256) void pad_cands(const int* __restrict__ off,
                                                 int* __restrict__ cand_i,
                                                 int* __restrict__ cand_j,
                                                 float* __restrict__ cand_v) {
  int t = blockIdx.x * 256 + threadIdx.x;
  if (t >= KCAND) return;
  int M = off[NCELLS];
  if (t >= M) { cand_i[t] = 0; cand_j[t] = 0; cand_v[t] = -1.0f; }
}

// ---------------------------------------------------------------------------
// 6) finalize — bit-exact (sequential fmaf chain matches BLAS order)
// ---------------------------------------------------------------------------
__global__ __launch_bounds__(256) void finalize_k(const float* __restrict__ ue,
                                                  const float* __restrict__ W,
                                                  const float* __restrict__ b,
                                                  const float* __restrict__ g,
                                                  const int* __restrict__ nz,
                                                  const int* __restrict__ cand_i,
                                                  const int* __restrict__ cand_j,
                                                  const float* __restrict__ cand_v,
                                                  float* __restrict__ out) {
  __shared__ float Ws[512];
  int tid = threadIdx.x;
  Ws[tid] = W[tid];
  Ws[tid + 256] = W[tid + 256];
  __syncthreads();

  int p = blockIdx.x * 256 + tid;
  if (p >= NTOT) return;

  int i, j;
  float wgt;
  if (p < EDGES) {
    i = nz[2 * p];
    j = nz[2 * p + 1];
    wgt = 1.0f;
  } else {
    int qq = p - EDGES;
    i = cand_i[qq];
    j = cand_j[qq];
    wgt = fmaxf(cand_v[qq], 0.0f);
  }

  const float4* ri = (const float4*)(ue + (size_t)i * DIMS);
  const float4* rj = (const float4*)(ue + (size_t)j * DIMS);
  float l0 = 0.f, l1 = 0.f;
#pragma unroll
  for (int kk = 0; kk < 32; ++kk) {
    float4 a = ri[kk];
    l0 = fmaf(a.x, Ws[kk * 4 + 0], l0);
    l0 = fmaf(a.y, Ws[kk * 4 + 1], l0);
    l0 = fmaf(a.z, Ws[kk * 4 + 2], l0);
    l0 = fmaf(a.w, Ws[kk * 4 + 3], l0);
    l1 = fmaf(a.x, Ws[256 + kk * 4 + 0], l1);
    l1 = fmaf(a.y, Ws[256 + kk * 4 + 1], l1);
    l1 = fmaf(a.z, Ws[256 + kk * 4 + 2], l1);
    l1 = fmaf(a.w, Ws[256 + kk * 4 + 3], l1);
  }
#pragma unroll
  for (int kk = 0; kk < 32; ++kk) {
    float4 a = rj[kk];
    l0 = fmaf(a.x, Ws[128 + kk * 4 + 0], l0);
    l0 = fmaf(a.y, Ws[128 + kk * 4 + 1], l0);
    l0 = fmaf(a.z, Ws[128 + kk * 4 + 2], l0);
    l0 = fmaf(a.w, Ws[128 + kk * 4 + 3], l0);
    l1 = fmaf(a.x, Ws[384 + kk * 4 + 0], l1);
    l1 = fmaf(a.y, Ws[384 + kk * 4 + 1], l1);
    l1 = fmaf(a.z, Ws[384 + kk * 4 + 2], l1);
    l1 = fmaf(a.w, Ws[384 + kk * 4 + 3], l1);
  }
  l0 += b[0];
  l1 += b[1];

  float s0 = l0 + g[2 * p];
  float s1 = l1 + g[2 * p + 1];
  float w = (s0 >= s1) ? wgt : 0.0f;

  out[p] = w;
  out[NTOT + p] = w;
  out[2 * NTOT + p] = w;
  out[3 * NTOT + 2 * p + 0] = (float)i;
  out[3 * NTOT + 2 * p + 1] = (float)j;
}

// ---------------------------------------------------------------------------
extern "C" void kernel_launch(void* const* d_in, const int* in_sizes, int n_in,
                              void* d_out, int out_size, void* d_ws, size_t ws_size,
                              hipStream_t stream) {
  (void)in_sizes; (void)n_in; (void)out_size; (void)ws_size;

  const float* user_emb = (const float*)d_in[0];
  const float* W        = (const float*)d_in[1];
  const float* b        = (const float*)d_in[2];
  const float* gnoise   = (const float*)d_in[3];
  const int*   nz       = (const int*)d_in[4];
  float* out = (float*)d_out;

  char* ws = (char*)d_ws;
  // ws layout (bytes)
  float*    u        = (float*)(ws + 0);                       //  4 MB
  unsigned* excl     = (unsigned*)(ws + (4u << 20));           //  8 MB
  int*      rowjq    = (int*)(ws + (12u << 20));               //  6 MB (32768*48*4)
  float*    rowvq    = (float*)(ws + (18u << 20));             //  6 MB
  int*      row_cnt4 = (int*)(ws + (24u << 20));               //  128 KB
  int*      row_off  = (int*)(ws + (24u << 20) + (256u << 10)); // 32769 ints
  int*      cand_i   = (int*)(ws + (25u << 20));               //  512 KB
  int*      cand_j   = (int*)(ws + (25u << 20) + (512u << 10));
  float*    cand_v   = (float*)(ws + (26u << 20));

  hipMemsetAsync(excl, 0, (size_t)N_USERS * 256 * sizeof(unsigned), stream);

  normalize_k<<<N_USERS / 256, 256, 0, stream>>>(user_emb, u);
  build_excl<<<EDGES / 256, 256, 0, stream>>>(nz, excl);
  pass_a<<<1024, 256, 0, stream>>>(u, excl, rowjq, rowvq, row_cnt4);
  scan_rows<<<1, 256, 0, stream>>>(row_cnt4, row_off);
  compact_rows<<<NCELLS / 256, 256, 0, stream>>>(row_cnt4, row_off, rowjq, rowvq,
                                                 cand_i, cand_j, cand_v);
  pad_cands<<<KCAND / 256, 256, 0, stream>>>(row_off, cand_i, cand_j, cand_v);
  finalize_k<<<NTOT / 256, 256, 0, stream>>>(user_emb, W, b, gnoise, nz,
                                             cand_i, cand_j, cand_v, out);
}